// Round 2
// baseline (245.485 us; speedup 1.0000x reference)
//
#include <hip/hip_runtime.h>

// WaveNet gated residual block, MI355X bf16-MFMA implementation (v2).
// v2 change: k1 gate computed fully in-register. Each wave owns channel rows
// {w*32..w*32+31} (tanh half) AND {128+w*32..+31} (sigmoid half), so the gate
// partners land in the same lane/register — no LDS, no barrier, no LDS gate
// pass. z stored as packed ushort4 (4 consecutive channels) per fragment.
//
// Pipeline:
//   pack_weights : f32 weights -> bf16 packed [M][K] rows (ws)
//   transpose_bt : f32 [B][C][T] -> bf16 [B][T][Cp] (d_out used as scratch;
//                  k2 rewrites every byte of d_out afterwards, same stream)
//   k1_gate      : x = Wconv*in(3 taps) + Wcond*cond + bias; gate; z -> ws (bf16)
//   k2_outskip   : [out;skip] = [Wout;Wskip] @ z + bias -> d_out (f32)

#define NB 8
#define NT 16000
#define CIN 128
#define CCOND 80
#define CCP 96
#define TT 64

typedef __attribute__((ext_vector_type(8))) __bf16 bf16x8;
typedef __attribute__((ext_vector_type(4))) float f32x4;
typedef __attribute__((ext_vector_type(4))) unsigned short u16x4;

__device__ __forceinline__ unsigned short f2bf(float f) {
  unsigned int u = __float_as_uint(f);
  return (unsigned short)((u + 0x7fffu + ((u >> 16) & 1u)) >> 16);  // RNE
}
__device__ __forceinline__ bf16x8 ldb8(const unsigned short* p) {
  return *reinterpret_cast<const bf16x8*>(p);
}

// ---- pack weights to bf16 [M][K] ----
__global__ void pack_weights(const float* __restrict__ wc, const float* __restrict__ wcd,
                             const float* __restrict__ wo, const float* __restrict__ wsk,
                             unsigned short* __restrict__ wpc,   // [256][384] k=tap*128+c
                             unsigned short* __restrict__ wpcd,  // [256][96]  zero-pad k>=80
                             unsigned short* __restrict__ wp2)   // [384][128] rows 0-127 Wout, 128-383 Wskip
{
  int idx = blockIdx.x * 256 + threadIdx.x;
  if (idx < 98304) {
    int o = idx / 384, k = idx - o * 384;
    int tap = k >> 7, c = k & 127;
    wpc[idx] = f2bf(wc[(o * 128 + c) * 3 + tap]);
  } else if (idx < 122880) {
    int i = idx - 98304;
    int o = i / 96, k = i - o * 96;
    wpcd[i] = f2bf(k < CCOND ? wcd[o * CCOND + k] : 0.f);
  } else if (idx < 172032) {
    int i = idx - 122880;
    int m = i >> 7, k = i & 127;
    wp2[i] = f2bf(m < 128 ? wo[m * 128 + k] : wsk[(m - 128) * 128 + k]);
  }
}

// ---- f32 [B][C][NT] -> bf16 [B][NT][Cp], zero pad c in [C,Cp) ----
__global__ void transpose_bt(const float* __restrict__ in, unsigned short* __restrict__ outT,
                             int C, int Cp)
{
  __shared__ float tile[32][33];
  int t0 = blockIdx.x * 32, c0 = blockIdx.y * 32, b = blockIdx.z;
  int tx = threadIdx.x & 31, ty = threadIdx.x >> 5;  // ty 0..7
  #pragma unroll
  for (int i = 0; i < 4; ++i) {
    int c = c0 + ty + i * 8;
    float v = 0.f;
    if (c < C) v = in[((size_t)b * C + c) * NT + t0 + tx];
    tile[ty + i * 8][tx] = v;           // tile[c_local][t_local]
  }
  __syncthreads();
  #pragma unroll
  for (int i = 0; i < 4; ++i) {
    int t = ty + i * 8;
    outT[((size_t)b * NT + t0 + t) * Cp + c0 + tx] = f2bf(tile[tx][t]);
  }
}

// ---- k1: conv + cond GEMM (M=256, N=64, K=480) + bias + in-register gate ----
// Wave w owns preact rows: mf=0,1 -> w*32+mf*16 (tanh); mf=2,3 -> 128+w*32+(mf-2)*16 (sigmoid).
__global__ __launch_bounds__(256, 4) void k1_gate(
    const unsigned short* __restrict__ wpc, const unsigned short* __restrict__ wpcd,
    const unsigned short* __restrict__ inT, const unsigned short* __restrict__ cdT,
    const float* __restrict__ bconv, unsigned short* __restrict__ zb)
{
  int b = blockIdx.y;
  int t0 = blockIdx.x * TT;
  int tid = threadIdx.x;
  int lane = tid & 63, w = tid >> 6;
  int l15 = lane & 15, g = lane >> 4;

  int rowb[4];
  rowb[0] = w * 32;       rowb[1] = w * 32 + 16;
  rowb[2] = 128 + w * 32; rowb[3] = 128 + w * 32 + 16;

  f32x4 acc[4][4] = {};

  // conv taps: x(t) += sum_c W[o][c][tap] * in[c][t - 8 + 4*tap]
  #pragma unroll
  for (int tap = 0; tap < 3; ++tap) {
    #pragma unroll
    for (int kc = 0; kc < 4; ++kc) {
      int k0 = kc * 32 + g * 8;
      bf16x8 bfr[4];
      #pragma unroll
      for (int nf = 0; nf < 4; ++nf) {
        int t = t0 + nf * 16 + l15 - 8 + tap * 4;
        bf16x8 v = {};
        if (t >= 0) v = ldb8(&inT[((size_t)b * NT + t) * CIN + k0]);
        bfr[nf] = v;
      }
      #pragma unroll
      for (int mf = 0; mf < 4; ++mf) {
        bf16x8 afr = ldb8(&wpc[(size_t)(rowb[mf] + l15) * 384 + tap * 128 + k0]);
        #pragma unroll
        for (int nf = 0; nf < 4; ++nf)
          acc[mf][nf] = __builtin_amdgcn_mfma_f32_16x16x32_bf16(afr, bfr[nf], acc[mf][nf], 0, 0, 0);
      }
    }
  }
  // cond (K padded 80->96)
  #pragma unroll
  for (int kc = 0; kc < 3; ++kc) {
    int k0 = kc * 32 + g * 8;
    bf16x8 bfr[4];
    #pragma unroll
    for (int nf = 0; nf < 4; ++nf) {
      int t = t0 + nf * 16 + l15;
      bfr[nf] = ldb8(&cdT[((size_t)b * NT + t) * CCP + k0]);
    }
    #pragma unroll
    for (int mf = 0; mf < 4; ++mf) {
      bf16x8 afr = ldb8(&wpcd[(size_t)(rowb[mf] + l15) * CCP + k0]);
      #pragma unroll
      for (int nf = 0; nf < 4; ++nf)
        acc[mf][nf] = __builtin_amdgcn_mfma_f32_16x16x32_bf16(afr, bfr[nf], acc[mf][nf], 0, 0, 0);
    }
  }

  // bias per accumulator row (D layout: col=lane&15, row=g*4+j)
  float bt[2][4], bs[2][4];
  #pragma unroll
  for (int mf = 0; mf < 2; ++mf)
    #pragma unroll
    for (int j = 0; j < 4; ++j) {
      bt[mf][j] = bconv[rowb[mf] + g * 4 + j];
      bs[mf][j] = bconv[rowb[mf + 2] + g * 4 + j];
    }

  // gate in-register: z[c] = tanh(x[c]) * sigmoid(x[c+128]); packed 4-ch store
  #pragma unroll
  for (int mf = 0; mf < 2; ++mf) {
    int c0 = rowb[mf] + g * 4;
    #pragma unroll
    for (int nf = 0; nf < 4; ++nf) {
      int t = t0 + nf * 16 + l15;
      u16x4 pk;
      #pragma unroll
      for (int j = 0; j < 4; ++j) {
        float a = acc[mf][nf][j] + bt[mf][j];
        float s = acc[mf + 2][nf][j] + bs[mf][j];
        float z = (1.f - 2.f / (1.f + __expf(2.f * a))) * (1.f / (1.f + __expf(-s)));
        pk[j] = f2bf(z);
      }
      *reinterpret_cast<u16x4*>(&zb[((size_t)b * NT + t) * CIN + c0]) = pk;
    }
  }
}

// ---- k2: [out;skip] = [Wout;Wskip](384x128) @ z + bias ----
__global__ __launch_bounds__(256) void k2_outskip(
    const unsigned short* __restrict__ wp2, const unsigned short* __restrict__ zb,
    const float* __restrict__ bout, const float* __restrict__ bskip,
    float* __restrict__ out)
{
  int b = blockIdx.y, t0 = blockIdx.x * TT, tid = threadIdx.x;
  int lane = tid & 63, w = tid >> 6, l15 = lane & 15, g = lane >> 4;
  int mbase = w * 96;                   // wave owns 96 of 384 stacked rows
  f32x4 acc[6][4] = {};
  #pragma unroll
  for (int kc = 0; kc < 4; ++kc) {
    int k0 = kc * 32 + g * 8;
    bf16x8 bfr[4];
    #pragma unroll
    for (int nf = 0; nf < 4; ++nf)
      bfr[nf] = ldb8(&zb[((size_t)b * NT + t0 + nf * 16 + l15) * CIN + k0]);
    #pragma unroll
    for (int mf = 0; mf < 6; ++mf) {
      bf16x8 afr = ldb8(&wp2[(size_t)(mbase + mf * 16 + l15) * 128 + k0]);
      #pragma unroll
      for (int nf = 0; nf < 4; ++nf)
        acc[mf][nf] = __builtin_amdgcn_mfma_f32_16x16x32_bf16(afr, bfr[nf], acc[mf][nf], 0, 0, 0);
    }
  }
  float* skipp = out + (size_t)NB * 128 * NT;
  #pragma unroll
  for (int mf = 0; mf < 6; ++mf) {
    int mrow = mbase + mf * 16 + g * 4;
    #pragma unroll
    for (int j = 0; j < 4; ++j) {
      int m = mrow + j;
      float bv;
      float* basep;
      if (m < 128) { bv = bout[m];        basep = out   + ((size_t)b * 128 + m) * NT; }
      else         { bv = bskip[m - 128]; basep = skipp + ((size_t)b * 256 + (m - 128)) * NT; }
      #pragma unroll
      for (int nf = 0; nf < 4; ++nf)
        basep[t0 + nf * 16 + l15] = acc[mf][nf][j] + bv;
    }
  }
}

extern "C" void kernel_launch(void* const* d_in, const int* in_sizes, int n_in,
                              void* d_out, int out_size, void* d_ws, size_t ws_size,
                              hipStream_t stream)
{
  const float* input = (const float*)d_in[0];
  const float* cond  = (const float*)d_in[1];
  const float* wconv = (const float*)d_in[2];
  const float* bconv = (const float*)d_in[3];
  const float* wcond = (const float*)d_in[4];
  const float* wout  = (const float*)d_in[5];
  const float* boutp = (const float*)d_in[6];
  const float* wskip = (const float*)d_in[7];
  const float* bskip = (const float*)d_in[8];
  float* out = (float*)d_out;

  // ws layout (bf16 elems): weights then z
  unsigned short* wpc  = (unsigned short*)d_ws;     //  98304
  unsigned short* wpcd = wpc + 98304;               //  24576
  unsigned short* wp2  = wpcd + 24576;              //  49152
  unsigned short* zb   = wp2 + 49152;               //  16,384,000
  // transposed activations live in d_out scratch (k2 rewrites all of d_out)
  unsigned short* inT  = (unsigned short*)d_out;    //  16,384,000 elems (32.77 MB)
  unsigned short* cdT  = inT + (size_t)16384000;    //  12,288,000 elems (24.58 MB)

  pack_weights<<<672, 256, 0, stream>>>(wconv, wcond, wout, wskip, wpc, wpcd, wp2);
  transpose_bt<<<dim3(500, 4, NB), 256, 0, stream>>>(input, inT, 128, 128);
  transpose_bt<<<dim3(500, 3, NB), 256, 0, stream>>>(cond, cdT, 80, CCP);
  k1_gate<<<dim3(250, NB), 256, 0, stream>>>(wpc, wpcd, inT, cdT, bconv, zb);
  k2_outskip<<<dim3(250, NB), 256, 0, stream>>>(wp2, zb, boutp, bskip, out);
}

// Round 3
// 236.513 us; speedup vs baseline: 1.0379x; 1.0379x over previous
//
#include <hip/hip_runtime.h>

// WaveNet gated residual block, MI355X bf16-MFMA implementation (v3).
// v3 change: z stored in a tiled layout z[b][t/16][c/8][t%16][c%8] so the
// in-register gate's u16x4 fragment stores are fully coalesced (2x256B
// contiguous per store instr) and k2's B-fragment loads are single 16B
// loads spanning 1KB contiguous per wave. No LDS anywhere in k1/k2.
//
// Pipeline:
//   pack_weights : f32 weights -> bf16 packed [M][K] rows (ws)
//   transpose_bt : f32 [B][C][T] -> bf16 [B][T][Cp] (d_out used as scratch;
//                  k2 rewrites every byte of d_out afterwards, same stream)
//   k1_gate      : x = Wconv*in(3 taps) + Wcond*cond + bias; gate; z -> ws (tiled bf16)
//   k2_outskip   : [out;skip] = [Wout;Wskip] @ z + bias -> d_out (f32)

#define NB 8
#define NT 16000
#define CIN 128
#define CCOND 80
#define CCP 96
#define TT 64
#define NTB 1000   // NT/16

typedef __attribute__((ext_vector_type(8))) __bf16 bf16x8;
typedef __attribute__((ext_vector_type(4))) float f32x4;
typedef __attribute__((ext_vector_type(4))) unsigned short u16x4;

__device__ __forceinline__ unsigned short f2bf(float f) {
  unsigned int u = __float_as_uint(f);
  return (unsigned short)((u + 0x7fffu + ((u >> 16) & 1u)) >> 16);  // RNE
}
__device__ __forceinline__ bf16x8 ldb8(const unsigned short* p) {
  return *reinterpret_cast<const bf16x8*>(p);
}

// ---- pack weights to bf16 [M][K] ----
__global__ void pack_weights(const float* __restrict__ wc, const float* __restrict__ wcd,
                             const float* __restrict__ wo, const float* __restrict__ wsk,
                             unsigned short* __restrict__ wpc,   // [256][384] k=tap*128+c
                             unsigned short* __restrict__ wpcd,  // [256][96]  zero-pad k>=80
                             unsigned short* __restrict__ wp2)   // [384][128] rows 0-127 Wout, 128-383 Wskip
{
  int idx = blockIdx.x * 256 + threadIdx.x;
  if (idx < 98304) {
    int o = idx / 384, k = idx - o * 384;
    int tap = k >> 7, c = k & 127;
    wpc[idx] = f2bf(wc[(o * 128 + c) * 3 + tap]);
  } else if (idx < 122880) {
    int i = idx - 98304;
    int o = i / 96, k = i - o * 96;
    wpcd[i] = f2bf(k < CCOND ? wcd[o * CCOND + k] : 0.f);
  } else if (idx < 172032) {
    int i = idx - 122880;
    int m = i >> 7, k = i & 127;
    wp2[i] = f2bf(m < 128 ? wo[m * 128 + k] : wsk[(m - 128) * 128 + k]);
  }
}

// ---- f32 [B][C][NT] -> bf16 [B][NT][Cp], zero pad c in [C,Cp) ----
__global__ void transpose_bt(const float* __restrict__ in, unsigned short* __restrict__ outT,
                             int C, int Cp)
{
  __shared__ float tile[32][33];
  int t0 = blockIdx.x * 32, c0 = blockIdx.y * 32, b = blockIdx.z;
  int tx = threadIdx.x & 31, ty = threadIdx.x >> 5;  // ty 0..7
  #pragma unroll
  for (int i = 0; i < 4; ++i) {
    int c = c0 + ty + i * 8;
    float v = 0.f;
    if (c < C) v = in[((size_t)b * C + c) * NT + t0 + tx];
    tile[ty + i * 8][tx] = v;           // tile[c_local][t_local]
  }
  __syncthreads();
  #pragma unroll
  for (int i = 0; i < 4; ++i) {
    int t = ty + i * 8;
    outT[((size_t)b * NT + t0 + t) * Cp + c0 + tx] = f2bf(tile[tx][t]);
  }
}

// ---- k1: conv + cond GEMM (M=256, N=64, K=480) + bias + in-register gate ----
// Wave w owns preact rows: mf=0,1 -> w*32+mf*16 (tanh); mf=2,3 -> 128+... (sigmoid).
// z written in tiled layout [b][tb][cg8][tl][8].
__global__ __launch_bounds__(256, 4) void k1_gate(
    const unsigned short* __restrict__ wpc, const unsigned short* __restrict__ wpcd,
    const unsigned short* __restrict__ inT, const unsigned short* __restrict__ cdT,
    const float* __restrict__ bconv, unsigned short* __restrict__ zb)
{
  int b = blockIdx.y;
  int t0 = blockIdx.x * TT;
  int tid = threadIdx.x;
  int lane = tid & 63, w = tid >> 6;
  int l15 = lane & 15, g = lane >> 4;

  int rowb[4];
  rowb[0] = w * 32;       rowb[1] = w * 32 + 16;
  rowb[2] = 128 + w * 32; rowb[3] = 128 + w * 32 + 16;

  f32x4 acc[4][4] = {};

  // conv taps: x(t) += sum_c W[o][c][tap] * in[c][t - 8 + 4*tap]
  #pragma unroll
  for (int tap = 0; tap < 3; ++tap) {
    #pragma unroll
    for (int kc = 0; kc < 4; ++kc) {
      int k0 = kc * 32 + g * 8;
      bf16x8 bfr[4];
      #pragma unroll
      for (int nf = 0; nf < 4; ++nf) {
        int t = t0 + nf * 16 + l15 - 8 + tap * 4;
        bf16x8 v = {};
        if (t >= 0) v = ldb8(&inT[((size_t)b * NT + t) * CIN + k0]);
        bfr[nf] = v;
      }
      #pragma unroll
      for (int mf = 0; mf < 4; ++mf) {
        bf16x8 afr = ldb8(&wpc[(size_t)(rowb[mf] + l15) * 384 + tap * 128 + k0]);
        #pragma unroll
        for (int nf = 0; nf < 4; ++nf)
          acc[mf][nf] = __builtin_amdgcn_mfma_f32_16x16x32_bf16(afr, bfr[nf], acc[mf][nf], 0, 0, 0);
      }
    }
  }
  // cond (K padded 80->96)
  #pragma unroll
  for (int kc = 0; kc < 3; ++kc) {
    int k0 = kc * 32 + g * 8;
    bf16x8 bfr[4];
    #pragma unroll
    for (int nf = 0; nf < 4; ++nf) {
      int t = t0 + nf * 16 + l15;
      bfr[nf] = ldb8(&cdT[((size_t)b * NT + t) * CCP + k0]);
    }
    #pragma unroll
    for (int mf = 0; mf < 4; ++mf) {
      bf16x8 afr = ldb8(&wpcd[(size_t)(rowb[mf] + l15) * CCP + k0]);
      #pragma unroll
      for (int nf = 0; nf < 4; ++nf)
        acc[mf][nf] = __builtin_amdgcn_mfma_f32_16x16x32_bf16(afr, bfr[nf], acc[mf][nf], 0, 0, 0);
    }
  }

  // bias per accumulator row (D layout: col=lane&15, row=g*4+j)
  float bt[2][4], bs[2][4];
  #pragma unroll
  for (int mf = 0; mf < 2; ++mf)
    #pragma unroll
    for (int j = 0; j < 4; ++j) {
      bt[mf][j] = bconv[rowb[mf] + g * 4 + j];
      bs[mf][j] = bconv[rowb[mf + 2] + g * 4 + j];
    }

  // gate in-register; store z tiled: [b][tb][cg8][tl=l15][8], u16x4 per lane.
  // c = w*32 + mf*16 + g*4 + j  ->  cg8 = w*4+mf*2+(g>>1), c&7 = (g&1)*4+j
  #pragma unroll
  for (int mf = 0; mf < 2; ++mf) {
    int cg8 = w * 4 + mf * 2 + (g >> 1);
    int ch4 = (g & 1) * 4;
    #pragma unroll
    for (int nf = 0; nf < 4; ++nf) {
      int tb = (t0 >> 4) + nf;
      u16x4 pk;
      #pragma unroll
      for (int j = 0; j < 4; ++j) {
        float a = acc[mf][nf][j] + bt[mf][j];
        float s = acc[mf + 2][nf][j] + bs[mf][j];
        float z = (1.f - 2.f / (1.f + __expf(2.f * a))) * (1.f / (1.f + __expf(-s)));
        pk[j] = f2bf(z);
      }
      *reinterpret_cast<u16x4*>(
          &zb[((((size_t)b * NTB + tb) * 16 + cg8) * 16 + l15) * 8 + ch4]) = pk;
    }
  }
}

// ---- k2: [out;skip] = [Wout;Wskip](384x128) @ z + bias ----
__global__ __launch_bounds__(256) void k2_outskip(
    const unsigned short* __restrict__ wp2, const unsigned short* __restrict__ zb,
    const float* __restrict__ bout, const float* __restrict__ bskip,
    float* __restrict__ out)
{
  int b = blockIdx.y, t0 = blockIdx.x * TT, tid = threadIdx.x;
  int lane = tid & 63, w = tid >> 6, l15 = lane & 15, g = lane >> 4;
  int mbase = w * 96;                   // wave owns 96 of 384 stacked rows
  f32x4 acc[6][4] = {};
  #pragma unroll
  for (int kc = 0; kc < 4; ++kc) {
    int k0 = kc * 32 + g * 8;
    bf16x8 bfr[4];
    #pragma unroll
    for (int nf = 0; nf < 4; ++nf)
      bfr[nf] = ldb8(&zb[((((size_t)b * NTB + (t0 >> 4) + nf) * 16 + (kc * 4 + g)) * 16 + l15) * 8]);
    #pragma unroll
    for (int mf = 0; mf < 6; ++mf) {
      bf16x8 afr = ldb8(&wp2[(size_t)(mbase + mf * 16 + l15) * 128 + k0]);
      #pragma unroll
      for (int nf = 0; nf < 4; ++nf)
        acc[mf][nf] = __builtin_amdgcn_mfma_f32_16x16x32_bf16(afr, bfr[nf], acc[mf][nf], 0, 0, 0);
    }
  }
  float* skipp = out + (size_t)NB * 128 * NT;
  #pragma unroll
  for (int mf = 0; mf < 6; ++mf) {
    int mrow = mbase + mf * 16 + g * 4;
    #pragma unroll
    for (int j = 0; j < 4; ++j) {
      int m = mrow + j;
      float bv;
      float* basep;
      if (m < 128) { bv = bout[m];        basep = out   + ((size_t)b * 128 + m) * NT; }
      else         { bv = bskip[m - 128]; basep = skipp + ((size_t)b * 256 + (m - 128)) * NT; }
      #pragma unroll
      for (int nf = 0; nf < 4; ++nf)
        basep[t0 + nf * 16 + l15] = acc[mf][nf][j] + bv;
    }
  }
}

extern "C" void kernel_launch(void* const* d_in, const int* in_sizes, int n_in,
                              void* d_out, int out_size, void* d_ws, size_t ws_size,
                              hipStream_t stream)
{
  const float* input = (const float*)d_in[0];
  const float* cond  = (const float*)d_in[1];
  const float* wconv = (const float*)d_in[2];
  const float* bconv = (const float*)d_in[3];
  const float* wcond = (const float*)d_in[4];
  const float* wout  = (const float*)d_in[5];
  const float* boutp = (const float*)d_in[6];
  const float* wskip = (const float*)d_in[7];
  const float* bskip = (const float*)d_in[8];
  float* out = (float*)d_out;

  // ws layout (bf16 elems): weights then z
  unsigned short* wpc  = (unsigned short*)d_ws;     //  98304
  unsigned short* wpcd = wpc + 98304;               //  24576
  unsigned short* wp2  = wpcd + 24576;              //  49152
  unsigned short* zb   = wp2 + 49152;               //  16,384,000 (tiled)
  // transposed activations live in d_out scratch (k2 rewrites all of d_out)
  unsigned short* inT  = (unsigned short*)d_out;    //  16,384,000 elems (32.77 MB)
  unsigned short* cdT  = inT + (size_t)16384000;    //  12,288,000 elems (24.58 MB)

  pack_weights<<<672, 256, 0, stream>>>(wconv, wcond, wout, wskip, wpc, wpcd, wp2);
  transpose_bt<<<dim3(500, 4, NB), 256, 0, stream>>>(input, inT, 128, 128);
  transpose_bt<<<dim3(500, 3, NB), 256, 0, stream>>>(cond, cdT, 80, CCP);
  k1_gate<<<dim3(250, NB), 256, 0, stream>>>(wpc, wpcd, inT, cdT, bconv, zb);
  k2_outskip<<<dim3(250, NB), 256, 0, stream>>>(wp2, zb, boutp, bskip, out);
}

// Round 4
// 175.433 us; speedup vs baseline: 1.3993x; 1.3482x over previous
//
#include <hip/hip_runtime.h>

// WaveNet gated residual block, MI355X bf16-MFMA implementation (v4).
// v4: FUSED k1+k2 kernel. z stays in LDS (XOR-swizzled); input/cond tiles are
// reg-staged into swizzled LDS once per block so all GEMM B-fragments are
// conflict-free ds_read_b128 (latency-bound -> LDS-fed). Requires transposed
// activations in d_ws (fused kernel writes all of d_out): needs ~57.7MB ws.
// Host branches on ws_size; fallback = v3 5-kernel path (d_out scratch).

#define NB 8
#define NT 16000
#define CIN 128
#define CCOND 80
#define CCP 96
#define TT 64
#define NTB 1000   // NT/16

typedef __attribute__((ext_vector_type(8))) __bf16 bf16x8;
typedef __attribute__((ext_vector_type(4))) float f32x4;
typedef __attribute__((ext_vector_type(4))) unsigned short u16x4;
typedef __attribute__((ext_vector_type(4))) unsigned int u32x4;

__device__ __forceinline__ unsigned short f2bf(float f) {
  unsigned int u = __float_as_uint(f);
  return (unsigned short)((u + 0x7fffu + ((u >> 16) & 1u)) >> 16);  // RNE
}
__device__ __forceinline__ bf16x8 ldb8(const unsigned short* p) {
  return *reinterpret_cast<const bf16x8*>(p);
}

// ---- pack weights to bf16 [M][K] ----
__global__ void pack_weights(const float* __restrict__ wc, const float* __restrict__ wcd,
                             const float* __restrict__ wo, const float* __restrict__ wsk,
                             unsigned short* __restrict__ wpc,   // [256][384] k=tap*128+c
                             unsigned short* __restrict__ wpcd,  // [256][96]  zero-pad k>=80
                             unsigned short* __restrict__ wp2)   // [384][128] rows 0-127 Wout, 128-383 Wskip
{
  int idx = blockIdx.x * 256 + threadIdx.x;
  if (idx < 98304) {
    int o = idx / 384, k = idx - o * 384;
    int tap = k >> 7, c = k & 127;
    wpc[idx] = f2bf(wc[(o * 128 + c) * 3 + tap]);
  } else if (idx < 122880) {
    int i = idx - 98304;
    int o = i / 96, k = i - o * 96;
    wpcd[i] = f2bf(k < CCOND ? wcd[o * CCOND + k] : 0.f);
  } else if (idx < 172032) {
    int i = idx - 122880;
    int m = i >> 7, k = i & 127;
    wp2[i] = f2bf(m < 128 ? wo[m * 128 + k] : wsk[(m - 128) * 128 + k]);
  }
}

// ---- f32 [B][C][NT] -> bf16 [B][NT][Cp], zero pad c in [C,Cp) ----
__global__ void transpose_bt(const float* __restrict__ in, unsigned short* __restrict__ outT,
                             int C, int Cp)
{
  __shared__ float tile[32][33];
  int t0 = blockIdx.x * 32, c0 = blockIdx.y * 32, b = blockIdx.z;
  int tx = threadIdx.x & 31, ty = threadIdx.x >> 5;  // ty 0..7
  #pragma unroll
  for (int i = 0; i < 4; ++i) {
    int c = c0 + ty + i * 8;
    float v = 0.f;
    if (c < C) v = in[((size_t)b * C + c) * NT + t0 + tx];
    tile[ty + i * 8][tx] = v;           // tile[c_local][t_local]
  }
  __syncthreads();
  #pragma unroll
  for (int i = 0; i < 4; ++i) {
    int t = ty + i * 8;
    outT[((size_t)b * NT + t0 + t) * Cp + c0 + tx] = f2bf(tile[tx][t]);
  }
}

// ======================= FUSED k1+k2 (v4) =======================
// LDS: ldsX [72 rows][256B] swizzled input tile (t0-8..t0+64), 18432B
//      ldsU union: cond tile [64][192B] (phase 1) / z tile [64][256B] (phase 2)
// Swizzle: 16B granule index ^= (row & mask); mask=7 for 256B rows, 3 for 192B.
__global__ __launch_bounds__(256, 3) void k12_fused(
    const unsigned short* __restrict__ wpc, const unsigned short* __restrict__ wpcd,
    const unsigned short* __restrict__ wp2,
    const unsigned short* __restrict__ inT, const unsigned short* __restrict__ cdT,
    const float* __restrict__ bconv, const float* __restrict__ bout,
    const float* __restrict__ bskip, float* __restrict__ out)
{
  __shared__ unsigned short ldsX_[9216];   // 18432 B
  __shared__ unsigned short ldsU_[8192];   // 16384 B
  char* ldsX = (char*)ldsX_;
  char* ldsU = (char*)ldsU_;

  int b = blockIdx.y;
  int t0 = blockIdx.x * TT;
  int tid = threadIdx.x;
  int lane = tid & 63, w = tid >> 6;
  int l15 = lane & 15, g = lane >> 4;

  // ---- stage input tile (72 rows x 128ch bf16), zero halo t<0 ----
  #pragma unroll
  for (int i = 0; i < 5; ++i) {
    int gi = i * 256 + tid;
    if (gi < 1152) {
      int r = gi >> 4, ch = gi & 15;
      int t = t0 - 8 + r;
      u32x4 v = {};
      if (t >= 0) v = *reinterpret_cast<const u32x4*>(&inT[((size_t)b * NT + t) * CIN + ch * 8]);
      *reinterpret_cast<u32x4*>(&ldsX[r * 256 + ((ch ^ (r & 7)) << 4)]) = v;
    }
  }
  // ---- stage cond tile (64 rows x 96ch bf16) ----
  #pragma unroll
  for (int i = 0; i < 3; ++i) {
    int gi = i * 256 + tid;
    int r = gi / 12, ch = gi - r * 12;
    u32x4 v = *reinterpret_cast<const u32x4*>(&cdT[((size_t)b * NT + t0 + r) * CCP + ch * 8]);
    *reinterpret_cast<u32x4*>(&ldsU[r * 192 + ((ch ^ (r & 3)) << 4)]) = v;
  }
  __syncthreads();

  int rowb[4];
  rowb[0] = w * 32;       rowb[1] = w * 32 + 16;
  rowb[2] = 128 + w * 32; rowb[3] = 128 + w * 32 + 16;

  f32x4 acc[4][4] = {};

  // ---- k1 GEMM: conv taps from ldsX ----
  #pragma unroll
  for (int tap = 0; tap < 3; ++tap) {
    #pragma unroll
    for (int kc = 0; kc < 4; ++kc) {
      int chunk = kc * 4 + g;
      int k0 = kc * 32 + g * 8;
      bf16x8 bfr[4];
      #pragma unroll
      for (int nf = 0; nf < 4; ++nf) {
        int tl = nf * 16 + l15 + tap * 4;
        bfr[nf] = *reinterpret_cast<const bf16x8*>(&ldsX[tl * 256 + ((chunk ^ (tl & 7)) << 4)]);
      }
      #pragma unroll
      for (int mf = 0; mf < 4; ++mf) {
        bf16x8 afr = ldb8(&wpc[(size_t)(rowb[mf] + l15) * 384 + tap * 128 + k0]);
        #pragma unroll
        for (int nf = 0; nf < 4; ++nf)
          acc[mf][nf] = __builtin_amdgcn_mfma_f32_16x16x32_bf16(afr, bfr[nf], acc[mf][nf], 0, 0, 0);
      }
    }
  }
  // ---- k1 GEMM: cond from ldsU ----
  #pragma unroll
  for (int kc = 0; kc < 3; ++kc) {
    int chunk = kc * 4 + g;
    int k0 = kc * 32 + g * 8;
    bf16x8 bfr[4];
    #pragma unroll
    for (int nf = 0; nf < 4; ++nf) {
      int r = nf * 16 + l15;
      bfr[nf] = *reinterpret_cast<const bf16x8*>(&ldsU[r * 192 + ((chunk ^ (r & 3)) << 4)]);
    }
    #pragma unroll
    for (int mf = 0; mf < 4; ++mf) {
      bf16x8 afr = ldb8(&wpcd[(size_t)(rowb[mf] + l15) * CCP + k0]);
      #pragma unroll
      for (int nf = 0; nf < 4; ++nf)
        acc[mf][nf] = __builtin_amdgcn_mfma_f32_16x16x32_bf16(afr, bfr[nf], acc[mf][nf], 0, 0, 0);
    }
  }

  // bias (D layout: col=lane&15, row=g*4+j)
  float bt[2][4], bs[2][4];
  #pragma unroll
  for (int mf = 0; mf < 2; ++mf)
    #pragma unroll
    for (int j = 0; j < 4; ++j) {
      bt[mf][j] = bconv[rowb[mf] + g * 4 + j];
      bs[mf][j] = bconv[rowb[mf + 2] + g * 4 + j];
    }

  __syncthreads();  // cond reads done; ldsU becomes z tile

  // ---- gate in-register -> z into swizzled ldsU [64 rows][256B] ----
  #pragma unroll
  for (int mf = 0; mf < 2; ++mf) {
    int cg = w * 4 + mf * 2 + (g >> 1);       // channel granule c>>3
    int off = (g & 1) * 8;                    // byte offset within granule
    #pragma unroll
    for (int nf = 0; nf < 4; ++nf) {
      int tl = nf * 16 + l15;
      u16x4 pk;
      #pragma unroll
      for (int j = 0; j < 4; ++j) {
        float a = acc[mf][nf][j] + bt[mf][j];
        float s = acc[mf + 2][nf][j] + bs[mf][j];
        float z = (1.f - 2.f / (1.f + __expf(2.f * a))) * (1.f / (1.f + __expf(-s)));
        pk[j] = f2bf(z);
      }
      *reinterpret_cast<u16x4*>(&ldsU[tl * 256 + ((cg ^ (tl & 7)) << 4) + off]) = pk;
    }
  }
  __syncthreads();

  // ---- k2 GEMM: [out;skip] = wp2 @ z ----
  f32x4 acc2[6][4] = {};
  int mbase = w * 96;
  #pragma unroll
  for (int kc = 0; kc < 4; ++kc) {
    int chunk = kc * 4 + g;
    int k0 = kc * 32 + g * 8;
    bf16x8 bfr[4];
    #pragma unroll
    for (int nf = 0; nf < 4; ++nf) {
      int r = nf * 16 + l15;
      bfr[nf] = *reinterpret_cast<const bf16x8*>(&ldsU[r * 256 + ((chunk ^ (r & 7)) << 4)]);
    }
    #pragma unroll
    for (int mf = 0; mf < 6; ++mf) {
      bf16x8 afr = ldb8(&wp2[(size_t)(mbase + mf * 16 + l15) * 128 + k0]);
      #pragma unroll
      for (int nf = 0; nf < 4; ++nf)
        acc2[mf][nf] = __builtin_amdgcn_mfma_f32_16x16x32_bf16(afr, bfr[nf], acc2[mf][nf], 0, 0, 0);
    }
  }
  float* skipp = out + (size_t)NB * 128 * NT;
  #pragma unroll
  for (int mf = 0; mf < 6; ++mf) {
    int mrow = mbase + mf * 16 + g * 4;
    #pragma unroll
    for (int j = 0; j < 4; ++j) {
      int m = mrow + j;
      float bv;
      float* basep;
      if (m < 128) { bv = bout[m];        basep = out   + ((size_t)b * 128 + m) * NT; }
      else         { bv = bskip[m - 128]; basep = skipp + ((size_t)b * 256 + (m - 128)) * NT; }
      #pragma unroll
      for (int nf = 0; nf < 4; ++nf)
        basep[t0 + nf * 16 + l15] = acc2[mf][nf][j] + bv;
    }
  }
}

// ======================= v3 fallback kernels =======================
__global__ __launch_bounds__(256, 4) void k1_gate_fb(
    const unsigned short* __restrict__ wpc, const unsigned short* __restrict__ wpcd,
    const unsigned short* __restrict__ inT, const unsigned short* __restrict__ cdT,
    const float* __restrict__ bconv, unsigned short* __restrict__ zb)
{
  int b = blockIdx.y;
  int t0 = blockIdx.x * TT;
  int tid = threadIdx.x;
  int lane = tid & 63, w = tid >> 6;
  int l15 = lane & 15, g = lane >> 4;
  int rowb[4];
  rowb[0] = w * 32;       rowb[1] = w * 32 + 16;
  rowb[2] = 128 + w * 32; rowb[3] = 128 + w * 32 + 16;
  f32x4 acc[4][4] = {};
  #pragma unroll
  for (int tap = 0; tap < 3; ++tap) {
    #pragma unroll
    for (int kc = 0; kc < 4; ++kc) {
      int k0 = kc * 32 + g * 8;
      bf16x8 bfr[4];
      #pragma unroll
      for (int nf = 0; nf < 4; ++nf) {
        int t = t0 + nf * 16 + l15 - 8 + tap * 4;
        bf16x8 v = {};
        if (t >= 0) v = ldb8(&inT[((size_t)b * NT + t) * CIN + k0]);
        bfr[nf] = v;
      }
      #pragma unroll
      for (int mf = 0; mf < 4; ++mf) {
        bf16x8 afr = ldb8(&wpc[(size_t)(rowb[mf] + l15) * 384 + tap * 128 + k0]);
        #pragma unroll
        for (int nf = 0; nf < 4; ++nf)
          acc[mf][nf] = __builtin_amdgcn_mfma_f32_16x16x32_bf16(afr, bfr[nf], acc[mf][nf], 0, 0, 0);
      }
    }
  }
  #pragma unroll
  for (int kc = 0; kc < 3; ++kc) {
    int k0 = kc * 32 + g * 8;
    bf16x8 bfr[4];
    #pragma unroll
    for (int nf = 0; nf < 4; ++nf) {
      int t = t0 + nf * 16 + l15;
      bfr[nf] = ldb8(&cdT[((size_t)b * NT + t) * CCP + k0]);
    }
    #pragma unroll
    for (int mf = 0; mf < 4; ++mf) {
      bf16x8 afr = ldb8(&wpcd[(size_t)(rowb[mf] + l15) * CCP + k0]);
      #pragma unroll
      for (int nf = 0; nf < 4; ++nf)
        acc[mf][nf] = __builtin_amdgcn_mfma_f32_16x16x32_bf16(afr, bfr[nf], acc[mf][nf], 0, 0, 0);
    }
  }
  float bt[2][4], bs[2][4];
  #pragma unroll
  for (int mf = 0; mf < 2; ++mf)
    #pragma unroll
    for (int j = 0; j < 4; ++j) {
      bt[mf][j] = bconv[rowb[mf] + g * 4 + j];
      bs[mf][j] = bconv[rowb[mf + 2] + g * 4 + j];
    }
  #pragma unroll
  for (int mf = 0; mf < 2; ++mf) {
    int cg8 = w * 4 + mf * 2 + (g >> 1);
    int ch4 = (g & 1) * 4;
    #pragma unroll
    for (int nf = 0; nf < 4; ++nf) {
      int tb = (t0 >> 4) + nf;
      u16x4 pk;
      #pragma unroll
      for (int j = 0; j < 4; ++j) {
        float a = acc[mf][nf][j] + bt[mf][j];
        float s = acc[mf + 2][nf][j] + bs[mf][j];
        float z = (1.f - 2.f / (1.f + __expf(2.f * a))) * (1.f / (1.f + __expf(-s)));
        pk[j] = f2bf(z);
      }
      *reinterpret_cast<u16x4*>(
          &zb[((((size_t)b * NTB + tb) * 16 + cg8) * 16 + l15) * 8 + ch4]) = pk;
    }
  }
}

__global__ __launch_bounds__(256) void k2_outskip_fb(
    const unsigned short* __restrict__ wp2, const unsigned short* __restrict__ zb,
    const float* __restrict__ bout, const float* __restrict__ bskip,
    float* __restrict__ out)
{
  int b = blockIdx.y, t0 = blockIdx.x * TT, tid = threadIdx.x;
  int lane = tid & 63, w = tid >> 6, l15 = lane & 15, g = lane >> 4;
  int mbase = w * 96;
  f32x4 acc[6][4] = {};
  #pragma unroll
  for (int kc = 0; kc < 4; ++kc) {
    int k0 = kc * 32 + g * 8;
    bf16x8 bfr[4];
    #pragma unroll
    for (int nf = 0; nf < 4; ++nf)
      bfr[nf] = ldb8(&zb[((((size_t)b * NTB + (t0 >> 4) + nf) * 16 + (kc * 4 + g)) * 16 + l15) * 8]);
    #pragma unroll
    for (int mf = 0; mf < 6; ++mf) {
      bf16x8 afr = ldb8(&wp2[(size_t)(mbase + mf * 16 + l15) * 128 + k0]);
      #pragma unroll
      for (int nf = 0; nf < 4; ++nf)
        acc[mf][nf] = __builtin_amdgcn_mfma_f32_16x16x32_bf16(afr, bfr[nf], acc[mf][nf], 0, 0, 0);
    }
  }
  float* skipp = out + (size_t)NB * 128 * NT;
  #pragma unroll
  for (int mf = 0; mf < 6; ++mf) {
    int mrow = mbase + mf * 16 + g * 4;
    #pragma unroll
    for (int j = 0; j < 4; ++j) {
      int m = mrow + j;
      float bv;
      float* basep;
      if (m < 128) { bv = bout[m];        basep = out   + ((size_t)b * 128 + m) * NT; }
      else         { bv = bskip[m - 128]; basep = skipp + ((size_t)b * 256 + (m - 128)) * NT; }
      #pragma unroll
      for (int nf = 0; nf < 4; ++nf)
        basep[t0 + nf * 16 + l15] = acc[mf][nf][j] + bv;
    }
  }
}

extern "C" void kernel_launch(void* const* d_in, const int* in_sizes, int n_in,
                              void* d_out, int out_size, void* d_ws, size_t ws_size,
                              hipStream_t stream)
{
  const float* input = (const float*)d_in[0];
  const float* cond  = (const float*)d_in[1];
  const float* wconv = (const float*)d_in[2];
  const float* bconv = (const float*)d_in[3];
  const float* wcond = (const float*)d_in[4];
  const float* wout  = (const float*)d_in[5];
  const float* boutp = (const float*)d_in[6];
  const float* wskip = (const float*)d_in[7];
  const float* bskip = (const float*)d_in[8];
  float* out = (float*)d_out;

  unsigned short* wpc  = (unsigned short*)d_ws;     //  98304
  unsigned short* wpcd = wpc + 98304;               //  24576
  unsigned short* wp2  = wpcd + 24576;              //  49152

  const size_t FUSED_WS = (size_t)(98304 + 24576 + 49152 + 16384000 + 12288000) * 2;

  if (ws_size >= FUSED_WS) {
    // fused path: transposed activations in ws
    unsigned short* inT = wp2 + 49152;              // 16,384,000 elems
    unsigned short* cdT = inT + (size_t)16384000;   // 12,288,000 elems
    pack_weights<<<672, 256, 0, stream>>>(wconv, wcond, wout, wskip, wpc, wpcd, wp2);
    transpose_bt<<<dim3(500, 4, NB), 256, 0, stream>>>(input, inT, 128, 128);
    transpose_bt<<<dim3(500, 3, NB), 256, 0, stream>>>(cond, cdT, 80, CCP);
    k12_fused<<<dim3(250, NB), 256, 0, stream>>>(wpc, wpcd, wp2, inT, cdT,
                                                 bconv, boutp, bskip, out);
  } else {
    // v3 fallback: transposed activations in d_out scratch, z in ws
    unsigned short* zb  = wp2 + 49152;              // 16,384,000 elems
    unsigned short* inT = (unsigned short*)d_out;
    unsigned short* cdT = inT + (size_t)16384000;
    pack_weights<<<672, 256, 0, stream>>>(wconv, wcond, wout, wskip, wpc, wpcd, wp2);
    transpose_bt<<<dim3(500, 4, NB), 256, 0, stream>>>(input, inT, 128, 128);
    transpose_bt<<<dim3(500, 3, NB), 256, 0, stream>>>(cond, cdT, 80, CCP);
    k1_gate_fb<<<dim3(250, NB), 256, 0, stream>>>(wpc, wpcd, inT, cdT, bconv, zb);
    k2_outskip_fb<<<dim3(250, NB), 256, 0, stream>>>(wp2, zb, boutp, bskip, out);
  }
}

// Round 5
// 166.525 us; speedup vs baseline: 1.4742x; 1.0535x over previous
//
#include <hip/hip_runtime.h>

// WaveNet gated residual block, MI355X bf16-MFMA implementation (v5).
// v5: k12 inner loops restructured as explicit software pipelines:
//   - k1 = 15 unified K-chunk steps (12 conv + 3 cond), 2-stage rotating
//     weight-frag registers (load s+1 while MFMA s) -> weight L2 latency
//     hidden under MFMA instead of serialized (v4: VGPR=84, everything
//     stalled on weight loads).
//   - k2 = 4 K-steps, 6-frag rotation; first batch preloaded during gate.
//   - __launch_bounds__(256,2) for register headroom.
// Transposes rewritten to write paired-bf16 u32 (no sub-64B write segments).

#define NB 8
#define NT 16000
#define CIN 128
#define CCOND 80
#define CCP 96
#define TT 64
#define NTB 1000   // NT/16

typedef __attribute__((ext_vector_type(8))) __bf16 bf16x8;
typedef __attribute__((ext_vector_type(4))) float f32x4;
typedef __attribute__((ext_vector_type(4))) unsigned short u16x4;
typedef __attribute__((ext_vector_type(4))) unsigned int u32x4;

__device__ __forceinline__ unsigned short f2bf(float f) {
  unsigned int u = __float_as_uint(f);
  return (unsigned short)((u + 0x7fffu + ((u >> 16) & 1u)) >> 16);  // RNE
}
__device__ __forceinline__ bf16x8 ldb8(const unsigned short* p) {
  return *reinterpret_cast<const bf16x8*>(p);
}

// ---- pack weights to bf16 [M][K] ----
__global__ void pack_weights(const float* __restrict__ wc, const float* __restrict__ wcd,
                             const float* __restrict__ wo, const float* __restrict__ wsk,
                             unsigned short* __restrict__ wpc,   // [256][384] k=tap*128+c
                             unsigned short* __restrict__ wpcd,  // [256][96]  zero-pad k>=80
                             unsigned short* __restrict__ wp2)   // [384][128] rows 0-127 Wout, 128-383 Wskip
{
  int idx = blockIdx.x * 256 + threadIdx.x;
  if (idx < 98304) {
    int o = idx / 384, k = idx - o * 384;
    int tap = k >> 7, c = k & 127;
    wpc[idx] = f2bf(wc[(o * 128 + c) * 3 + tap]);
  } else if (idx < 122880) {
    int i = idx - 98304;
    int o = i / 96, k = i - o * 96;
    wpcd[i] = f2bf(k < CCOND ? wcd[o * CCOND + k] : 0.f);
  } else if (idx < 172032) {
    int i = idx - 122880;
    int m = i >> 7, k = i & 127;
    wp2[i] = f2bf(m < 128 ? wo[m * 128 + k] : wsk[(m - 128) * 128 + k]);
  }
}

// ---- input f32 [B][128][NT] -> bf16 [B][NT][128], paired-u32 stores ----
__global__ void transpose_in64(const float* __restrict__ in, unsigned short* __restrict__ outT)
{
  __shared__ float tile[64][33];
  int t0 = blockIdx.x * 32, c0 = blockIdx.y * 64, b = blockIdx.z;
  int tx = threadIdx.x & 31, ty = threadIdx.x >> 5;  // ty 0..7
  #pragma unroll
  for (int i = 0; i < 8; ++i) {
    int c = c0 + i * 8 + ty;
    tile[i * 8 + ty][tx] = in[((size_t)b * CIN + c) * NT + t0 + tx];
  }
  __syncthreads();
  #pragma unroll
  for (int i = 0; i < 4; ++i) {
    int t = i * 8 + ty;
    unsigned int pk = (unsigned int)f2bf(tile[2 * tx][t]) |
                      ((unsigned int)f2bf(tile[2 * tx + 1][t]) << 16);
    *reinterpret_cast<unsigned int*>(&outT[((size_t)b * NT + t0 + t) * CIN + c0 + 2 * tx]) = pk;
  }
}

// ---- cond f32 [B][80][NT] -> bf16 [B][NT][96] (zero-pad), paired-u32 stores ----
__global__ void transpose_cd(const float* __restrict__ in, unsigned short* __restrict__ outT)
{
  __shared__ float tile[96][33];
  int t0 = blockIdx.x * 32, b = blockIdx.y;
  int tid = threadIdx.x;
  #pragma unroll
  for (int i = 0; i < 12; ++i) {
    int j = i * 256 + tid;
    int c = j >> 5, t = j & 31;
    float v = 0.f;
    if (c < CCOND) v = in[((size_t)b * CCOND + c) * NT + t0 + t];
    tile[c][t] = v;
  }
  __syncthreads();
  #pragma unroll
  for (int i = 0; i < 6; ++i) {
    int j = i * 256 + tid;
    int t = j / 48, cp = j - t * 48;
    unsigned int pk = (unsigned int)f2bf(tile[2 * cp][t]) |
                      ((unsigned int)f2bf(tile[2 * cp + 1][t]) << 16);
    *reinterpret_cast<unsigned int*>(&outT[((size_t)b * NT + t0 + t) * CCP + 2 * cp]) = pk;
  }
}

// ======================= FUSED k1+k2 (v5) =======================
__global__ __launch_bounds__(256, 2) void k12_fused(
    const unsigned short* __restrict__ wpc, const unsigned short* __restrict__ wpcd,
    const unsigned short* __restrict__ wp2,
    const unsigned short* __restrict__ inT, const unsigned short* __restrict__ cdT,
    const float* __restrict__ bconv, const float* __restrict__ bout,
    const float* __restrict__ bskip, float* __restrict__ out)
{
  __shared__ unsigned short ldsX_[9216];   // 18432 B: input tile [72 rows][256B] swizzled
  __shared__ unsigned short ldsU_[8192];   // 16384 B: cond [64][192B] then z [64][256B]
  char* ldsX = (char*)ldsX_;
  char* ldsU = (char*)ldsU_;

  int b = blockIdx.y;
  int t0 = blockIdx.x * TT;
  int tid = threadIdx.x;
  int lane = tid & 63, w = tid >> 6;
  int l15 = lane & 15, g = lane >> 4;

  // ---- stage input tile (72 rows x 128ch bf16), zero halo t<0 ----
  #pragma unroll
  for (int i = 0; i < 5; ++i) {
    int gi = i * 256 + tid;
    if (gi < 1152) {
      int r = gi >> 4, ch = gi & 15;
      int t = t0 - 8 + r;
      u32x4 v = {};
      if (t >= 0) v = *reinterpret_cast<const u32x4*>(&inT[((size_t)b * NT + t) * CIN + ch * 8]);
      *reinterpret_cast<u32x4*>(&ldsX[r * 256 + ((ch ^ (r & 7)) << 4)]) = v;
    }
  }
  // ---- stage cond tile (64 rows x 96ch bf16) ----
  #pragma unroll
  for (int i = 0; i < 3; ++i) {
    int gi = i * 256 + tid;
    int r = gi / 12, ch = gi - r * 12;
    u32x4 v = *reinterpret_cast<const u32x4*>(&cdT[((size_t)b * NT + t0 + r) * CCP + ch * 8]);
    *reinterpret_cast<u32x4*>(&ldsU[r * 192 + ((ch ^ (r & 3)) << 4)]) = v;
  }
  __syncthreads();

  int rowb[4];
  rowb[0] = w * 32;       rowb[1] = w * 32 + 16;
  rowb[2] = 128 + w * 32; rowb[3] = 128 + w * 32 + 16;

  f32x4 acc[4][4] = {};

  // unified k1: 15 K-chunk steps (s<12: conv tap s>>2, kc s&3; s>=12: cond kc s-12)
  auto ldw1 = [&](int s, int mf) -> bf16x8 {
    if (s < 12) {
      int tap = s >> 2, kc = s & 3;
      return ldb8(&wpc[(size_t)(rowb[mf] + l15) * 384 + tap * 128 + kc * 32 + g * 8]);
    } else {
      int kc = s - 12;
      return ldb8(&wpcd[(size_t)(rowb[mf] + l15) * CCP + kc * 32 + g * 8]);
    }
  };
  auto ldb1 = [&](int s, int nf) -> bf16x8 {
    if (s < 12) {
      int tap = s >> 2, kc = s & 3;
      int chunk = kc * 4 + g;
      int tl = nf * 16 + l15 + tap * 4;
      return *reinterpret_cast<const bf16x8*>(&ldsX[tl * 256 + ((chunk ^ (tl & 7)) << 4)]);
    } else {
      int kc = s - 12;
      int chunk = kc * 4 + g;
      int r = nf * 16 + l15;
      return *reinterpret_cast<const bf16x8*>(&ldsU[r * 192 + ((chunk ^ (r & 3)) << 4)]);
    }
  };

  bf16x8 wfA[4], wfB[4];
  #pragma unroll
  for (int mf = 0; mf < 4; ++mf) wfA[mf] = ldw1(0, mf);

  #pragma unroll
  for (int s = 0; s < 15; ++s) {
    bf16x8* cur = (s & 1) ? wfB : wfA;
    bf16x8* nxt = (s & 1) ? wfA : wfB;
    if (s < 14) {
      #pragma unroll
      for (int mf = 0; mf < 4; ++mf) nxt[mf] = ldw1(s + 1, mf);
    }
    bf16x8 bfr[4];
    #pragma unroll
    for (int nf = 0; nf < 4; ++nf) bfr[nf] = ldb1(s, nf);
    #pragma unroll
    for (int mf = 0; mf < 4; ++mf)
      #pragma unroll
      for (int nf = 0; nf < 4; ++nf)
        acc[mf][nf] = __builtin_amdgcn_mfma_f32_16x16x32_bf16(cur[mf], bfr[nf], acc[mf][nf], 0, 0, 0);
  }

  // bias (D layout: col=lane&15, row=g*4+j)
  float bt[2][4], bs[2][4];
  #pragma unroll
  for (int mf = 0; mf < 2; ++mf)
    #pragma unroll
    for (int j = 0; j < 4; ++j) {
      bt[mf][j] = bconv[rowb[mf] + g * 4 + j];
      bs[mf][j] = bconv[rowb[mf + 2] + g * 4 + j];
    }

  // preload k2 weights (kc=0) so their latency hides under the gate
  int mbase = w * 96;
  bf16x8 w2A[6], w2B[6];
  #pragma unroll
  for (int mf = 0; mf < 6; ++mf)
    w2A[mf] = ldb8(&wp2[(size_t)(mbase + mf * 16 + l15) * 128 + g * 8]);

  __syncthreads();  // cond reads done; ldsU becomes z tile

  // ---- gate in-register -> z into swizzled ldsU [64 rows][256B] ----
  #pragma unroll
  for (int mf = 0; mf < 2; ++mf) {
    int cg = w * 4 + mf * 2 + (g >> 1);       // channel granule c>>3
    int off = (g & 1) * 8;                    // byte offset within granule
    #pragma unroll
    for (int nf = 0; nf < 4; ++nf) {
      int tl = nf * 16 + l15;
      u16x4 pk;
      #pragma unroll
      for (int j = 0; j < 4; ++j) {
        float a = acc[mf][nf][j] + bt[mf][j];
        float s = acc[mf + 2][nf][j] + bs[mf][j];
        float z = (1.f - 2.f / (1.f + __expf(2.f * a))) * (1.f / (1.f + __expf(-s)));
        pk[j] = f2bf(z);
      }
      *reinterpret_cast<u16x4*>(&ldsU[tl * 256 + ((cg ^ (tl & 7)) << 4) + off]) = pk;
    }
  }
  __syncthreads();

  // ---- k2 GEMM: [out;skip] = wp2 @ z, 4 K-steps with weight rotation ----
  f32x4 acc2[6][4] = {};
  #pragma unroll
  for (int kc = 0; kc < 4; ++kc) {
    bf16x8* cur = (kc & 1) ? w2B : w2A;
    bf16x8* nxt = (kc & 1) ? w2A : w2B;
    if (kc < 3) {
      #pragma unroll
      for (int mf = 0; mf < 6; ++mf)
        nxt[mf] = ldb8(&wp2[(size_t)(mbase + mf * 16 + l15) * 128 + (kc + 1) * 32 + g * 8]);
    }
    bf16x8 bfr[4];
    #pragma unroll
    for (int nf = 0; nf < 4; ++nf) {
      int r = nf * 16 + l15;
      bfr[nf] = *reinterpret_cast<const bf16x8*>(&ldsU[r * 256 + (((kc * 4 + g) ^ (r & 7)) << 4)]);
    }
    #pragma unroll
    for (int mf = 0; mf < 6; ++mf)
      #pragma unroll
      for (int nf = 0; nf < 4; ++nf)
        acc2[mf][nf] = __builtin_amdgcn_mfma_f32_16x16x32_bf16(cur[mf], bfr[nf], acc2[mf][nf], 0, 0, 0);
  }

  float* skipp = out + (size_t)NB * 128 * NT;
  #pragma unroll
  for (int mf = 0; mf < 6; ++mf) {
    int mrow = mbase + mf * 16 + g * 4;
    #pragma unroll
    for (int j = 0; j < 4; ++j) {
      int m = mrow + j;
      float bv;
      float* basep;
      if (m < 128) { bv = bout[m];        basep = out   + ((size_t)b * 128 + m) * NT; }
      else         { bv = bskip[m - 128]; basep = skipp + ((size_t)b * 256 + (m - 128)) * NT; }
      #pragma unroll
      for (int nf = 0; nf < 4; ++nf)
        basep[t0 + nf * 16 + l15] = acc2[mf][nf][j] + bv;
    }
  }
}

// ======================= v3 fallback kernels =======================
__global__ __launch_bounds__(256, 4) void k1_gate_fb(
    const unsigned short* __restrict__ wpc, const unsigned short* __restrict__ wpcd,
    const unsigned short* __restrict__ inT, const unsigned short* __restrict__ cdT,
    const float* __restrict__ bconv, unsigned short* __restrict__ zb)
{
  int b = blockIdx.y;
  int t0 = blockIdx.x * TT;
  int tid = threadIdx.x;
  int lane = tid & 63, w = tid >> 6;
  int l15 = lane & 15, g = lane >> 4;
  int rowb[4];
  rowb[0] = w * 32;       rowb[1] = w * 32 + 16;
  rowb[2] = 128 + w * 32; rowb[3] = 128 + w * 32 + 16;
  f32x4 acc[4][4] = {};
  #pragma unroll
  for (int tap = 0; tap < 3; ++tap) {
    #pragma unroll
    for (int kc = 0; kc < 4; ++kc) {
      int k0 = kc * 32 + g * 8;
      bf16x8 bfr[4];
      #pragma unroll
      for (int nf = 0; nf < 4; ++nf) {
        int t = t0 + nf * 16 + l15 - 8 + tap * 4;
        bf16x8 v = {};
        if (t >= 0) v = ldb8(&inT[((size_t)b * NT + t) * CIN + k0]);
        bfr[nf] = v;
      }
      #pragma unroll
      for (int mf = 0; mf < 4; ++mf) {
        bf16x8 afr = ldb8(&wpc[(size_t)(rowb[mf] + l15) * 384 + tap * 128 + k0]);
        #pragma unroll
        for (int nf = 0; nf < 4; ++nf)
          acc[mf][nf] = __builtin_amdgcn_mfma_f32_16x16x32_bf16(afr, bfr[nf], acc[mf][nf], 0, 0, 0);
      }
    }
  }
  #pragma unroll
  for (int kc = 0; kc < 3; ++kc) {
    int k0 = kc * 32 + g * 8;
    bf16x8 bfr[4];
    #pragma unroll
    for (int nf = 0; nf < 4; ++nf) {
      int t = t0 + nf * 16 + l15;
      bfr[nf] = ldb8(&cdT[((size_t)b * NT + t) * CCP + k0]);
    }
    #pragma unroll
    for (int mf = 0; mf < 4; ++mf) {
      bf16x8 afr = ldb8(&wpcd[(size_t)(rowb[mf] + l15) * CCP + k0]);
      #pragma unroll
      for (int nf = 0; nf < 4; ++nf)
        acc[mf][nf] = __builtin_amdgcn_mfma_f32_16x16x32_bf16(afr, bfr[nf], acc[mf][nf], 0, 0, 0);
    }
  }
  float bt[2][4], bs[2][4];
  #pragma unroll
  for (int mf = 0; mf < 2; ++mf)
    #pragma unroll
    for (int j = 0; j < 4; ++j) {
      bt[mf][j] = bconv[rowb[mf] + g * 4 + j];
      bs[mf][j] = bconv[rowb[mf + 2] + g * 4 + j];
    }
  #pragma unroll
  for (int mf = 0; mf < 2; ++mf) {
    int cg8 = w * 4 + mf * 2 + (g >> 1);
    int ch4 = (g & 1) * 4;
    #pragma unroll
    for (int nf = 0; nf < 4; ++nf) {
      int tb = (t0 >> 4) + nf;
      u16x4 pk;
      #pragma unroll
      for (int j = 0; j < 4; ++j) {
        float a = acc[mf][nf][j] + bt[mf][j];
        float s = acc[mf + 2][nf][j] + bs[mf][j];
        float z = (1.f - 2.f / (1.f + __expf(2.f * a))) * (1.f / (1.f + __expf(-s)));
        pk[j] = f2bf(z);
      }
      *reinterpret_cast<u16x4*>(
          &zb[((((size_t)b * NTB + tb) * 16 + cg8) * 16 + l15) * 8 + ch4]) = pk;
    }
  }
}

__global__ __launch_bounds__(256) void k2_outskip_fb(
    const unsigned short* __restrict__ wp2, const unsigned short* __restrict__ zb,
    const float* __restrict__ bout, const float* __restrict__ bskip,
    float* __restrict__ out)
{
  int b = blockIdx.y, t0 = blockIdx.x * TT, tid = threadIdx.x;
  int lane = tid & 63, w = tid >> 6, l15 = lane & 15, g = lane >> 4;
  int mbase = w * 96;
  f32x4 acc[6][4] = {};
  #pragma unroll
  for (int kc = 0; kc < 4; ++kc) {
    int k0 = kc * 32 + g * 8;
    bf16x8 bfr[4];
    #pragma unroll
    for (int nf = 0; nf < 4; ++nf)
      bfr[nf] = ldb8(&zb[((((size_t)b * NTB + (t0 >> 4) + nf) * 16 + (kc * 4 + g)) * 16 + l15) * 8]);
    #pragma unroll
    for (int mf = 0; mf < 6; ++mf) {
      bf16x8 afr = ldb8(&wp2[(size_t)(mbase + mf * 16 + l15) * 128 + k0]);
      #pragma unroll
      for (int nf = 0; nf < 4; ++nf)
        acc[mf][nf] = __builtin_amdgcn_mfma_f32_16x16x32_bf16(afr, bfr[nf], acc[mf][nf], 0, 0, 0);
    }
  }
  float* skipp = out + (size_t)NB * 128 * NT;
  #pragma unroll
  for (int mf = 0; mf < 6; ++mf) {
    int mrow = mbase + mf * 16 + g * 4;
    #pragma unroll
    for (int j = 0; j < 4; ++j) {
      int m = mrow + j;
      float bv;
      float* basep;
      if (m < 128) { bv = bout[m];        basep = out   + ((size_t)b * 128 + m) * NT; }
      else         { bv = bskip[m - 128]; basep = skipp + ((size_t)b * 256 + (m - 128)) * NT; }
      #pragma unroll
      for (int nf = 0; nf < 4; ++nf)
        basep[t0 + nf * 16 + l15] = acc[mf][nf][j] + bv;
    }
  }
}

extern "C" void kernel_launch(void* const* d_in, const int* in_sizes, int n_in,
                              void* d_out, int out_size, void* d_ws, size_t ws_size,
                              hipStream_t stream)
{
  const float* input = (const float*)d_in[0];
  const float* cond  = (const float*)d_in[1];
  const float* wconv = (const float*)d_in[2];
  const float* bconv = (const float*)d_in[3];
  const float* wcond = (const float*)d_in[4];
  const float* wout  = (const float*)d_in[5];
  const float* boutp = (const float*)d_in[6];
  const float* wskip = (const float*)d_in[7];
  const float* bskip = (const float*)d_in[8];
  float* out = (float*)d_out;

  unsigned short* wpc  = (unsigned short*)d_ws;     //  98304
  unsigned short* wpcd = wpc + 98304;               //  24576
  unsigned short* wp2  = wpcd + 24576;              //  49152

  const size_t FUSED_WS = (size_t)(98304 + 24576 + 49152 + 16384000 + 12288000) * 2;

  if (ws_size >= FUSED_WS) {
    // fused path: transposed activations in ws
    unsigned short* inT = wp2 + 49152;              // 16,384,000 elems
    unsigned short* cdT = inT + (size_t)16384000;   // 12,288,000 elems
    pack_weights<<<672, 256, 0, stream>>>(wconv, wcond, wout, wskip, wpc, wpcd, wp2);
    transpose_in64<<<dim3(500, 2, NB), 256, 0, stream>>>(input, inT);
    transpose_cd<<<dim3(500, NB), 256, 0, stream>>>(cond, cdT);
    k12_fused<<<dim3(250, NB), 256, 0, stream>>>(wpc, wpcd, wp2, inT, cdT,
                                                 bconv, boutp, bskip, out);
  } else {
    // fallback: transposed activations in d_out scratch, z in ws
    unsigned short* zb  = wp2 + 49152;              // 16,384,000 elems
    unsigned short* inT = (unsigned short*)d_out;
    unsigned short* cdT = inT + (size_t)16384000;
    pack_weights<<<672, 256, 0, stream>>>(wconv, wcond, wout, wskip, wpc, wpcd, wp2);
    transpose_in64<<<dim3(500, 2, NB), 256, 0, stream>>>(input, inT);
    transpose_cd<<<dim3(500, NB), 256, 0, stream>>>(cond, cdT);
    k1_gate_fb<<<dim3(250, NB), 256, 0, stream>>>(wpc, wpcd, inT, cdT, bconv, zb);
    k2_outskip_fb<<<dim3(250, NB), 256, 0, stream>>>(wp2, zb, boutp, bskip, out);
  }
}